// Round 1
// baseline (432.383 us; speedup 1.0000x reference)
//
#include <hip/hip_runtime.h>
#include <stdint.h>

#define BT 4096
#define DMODEL 2048
#define FDIM 1024
#define NEXP 8
#define NA (BT * 2)

typedef __attribute__((ext_vector_type(8))) __bf16 bf16x8;
typedef __attribute__((ext_vector_type(4))) float f32x4;

__device__ __forceinline__ unsigned short f2bf(float f) {
  union { float f; unsigned int u; } v; v.f = f;
  unsigned int u = v.u;
  unsigned int r = (u + 0x7fffu + ((u >> 16) & 1u)) >> 16;
  return (unsigned short)r;
}
__device__ __forceinline__ float bf2f(unsigned short h) {
  union { unsigned int u; float f; } v; v.u = ((unsigned int)h) << 16;
  return v.f;
}

__device__ __forceinline__ void g2l16(const void* g, void* l) {
  __builtin_amdgcn_global_load_lds((const __attribute__((address_space(1))) void*)g,
                                   (__attribute__((address_space(3))) void*)l, 16, 0, 0);
}

// ---------------- small kernels ----------------

__global__ void k_zero(int* counts, int* cursors) {
  int i = threadIdx.x;
  if (i < NEXP) { counts[i] = 0; cursors[i] = 0; }
}

__global__ void k_convert_x(const float* __restrict__ x, unsigned short* __restrict__ xbf) {
  size_t i = ((size_t)blockIdx.x * 256 + threadIdx.x) * 8;
  float4 a = *(const float4*)(x + i);
  float4 b = *(const float4*)(x + i + 4);
  ushort4 lo = make_ushort4(f2bf(a.x), f2bf(a.y), f2bf(a.z), f2bf(a.w));
  ushort4 hi = make_ushort4(f2bf(b.x), f2bf(b.y), f2bf(b.z), f2bf(b.w));
  *(ushort4*)(xbf + i) = lo;
  *(ushort4*)(xbf + i + 4) = hi;
}

// transpose+convert: src [E][K][N] f32  ->  dst [E][N][K] bf16
__global__ void k_transpose(const float* __restrict__ src, unsigned short* __restrict__ dst,
                            int K, int N) {
  __shared__ float tile[64][65];
  int e = blockIdx.z;
  src += (size_t)e * K * N;
  dst += (size_t)e * K * N;
  int n0 = blockIdx.x * 64, k0 = blockIdx.y * 64;
  int rr = threadIdx.x >> 4, cc = threadIdx.x & 15;
#pragma unroll
  for (int i = 0; i < 4; i++) {
    int k = rr + i * 16;
    float4 v = *(const float4*)(src + (size_t)(k0 + k) * N + n0 + cc * 4);
    tile[k][cc * 4 + 0] = v.x; tile[k][cc * 4 + 1] = v.y;
    tile[k][cc * 4 + 2] = v.z; tile[k][cc * 4 + 3] = v.w;
  }
  __syncthreads();
#pragma unroll
  for (int i = 0; i < 4; i++) {
    int n = rr + i * 16;
    ushort4 o = make_ushort4(f2bf(tile[cc * 4 + 0][n]), f2bf(tile[cc * 4 + 1][n]),
                             f2bf(tile[cc * 4 + 2][n]), f2bf(tile[cc * 4 + 3][n]));
    *(ushort4*)(dst + (size_t)(n0 + n) * K + k0 + cc * 4) = o;
  }
}

__global__ void k_router(const float* __restrict__ x, const float* __restrict__ rw,
                         int* __restrict__ tok_e, float* __restrict__ tok_w,
                         int* __restrict__ counts) {
  int wid = threadIdx.x >> 6;
  int lane = threadIdx.x & 63;
  int t = blockIdx.x * 4 + wid;
  float acc[8];
#pragma unroll
  for (int e = 0; e < 8; e++) acc[e] = 0.0f;
  const float* xr = x + (size_t)t * DMODEL;
  for (int d = lane; d < DMODEL; d += 64) {
    float xv = xr[d];
    const float4* r4 = (const float4*)(rw + d * NEXP);
    float4 ra = r4[0], rb = r4[1];
    acc[0] += xv * ra.x; acc[1] += xv * ra.y; acc[2] += xv * ra.z; acc[3] += xv * ra.w;
    acc[4] += xv * rb.x; acc[5] += xv * rb.y; acc[6] += xv * rb.z; acc[7] += xv * rb.w;
  }
#pragma unroll
  for (int e = 0; e < 8; e++) {
    float v = acc[e];
#pragma unroll
    for (int off = 32; off > 0; off >>= 1) v += __shfl_xor(v, off);
    acc[e] = v;
  }
  if (lane == 0) {
    int e0 = 0; float s0 = acc[0];
#pragma unroll
    for (int e = 1; e < 8; e++) if (acc[e] > s0) { s0 = acc[e]; e0 = e; }
    int e1 = (e0 == 0) ? 1 : 0; float s1 = acc[e1];
#pragma unroll
    for (int e = 0; e < 8; e++) if (e != e0 && acc[e] > s1) { s1 = acc[e]; e1 = e; }
    // renormalized top-2 softmax: w0 = e^{s0} / (e^{s0} + e^{s1})
    float w0 = 1.0f / (1.0f + __expf(s1 - s0));
    tok_e[t * 2] = e0; tok_e[t * 2 + 1] = e1;
    tok_w[t * 2] = w0; tok_w[t * 2 + 1] = 1.0f - w0;
    atomicAdd(&counts[e0], 1);
    atomicAdd(&counts[e1], 1);
  }
}

__global__ void k_scan(const int* __restrict__ counts, int* __restrict__ offsets) {
  if (threadIdx.x == 0) {
    int s = 0;
    for (int e = 0; e < NEXP; e++) { offsets[e] = s; s += counts[e]; }
    offsets[NEXP] = s;
  }
}

__global__ void k_scatter(const int* __restrict__ tok_e, const float* __restrict__ tok_w,
                          const int* __restrict__ offsets, int* __restrict__ cursors,
                          int* __restrict__ assign_token, float* __restrict__ assign_w,
                          int* __restrict__ tok2pos) {
  int i = blockIdx.x * 256 + threadIdx.x;
  if (i >= NA) return;
  int e = tok_e[i];
  int pos = offsets[e] + atomicAdd(&cursors[e], 1);
  assign_token[pos] = i >> 1;
  assign_w[pos] = tok_w[i];
  tok2pos[i] = pos;
}

// ---------------- GEMM1: act = silu(Xg @ Wg) * (Xg @ Wu), per expert ----------------
// A: gathered x rows (bf16, [token][D]); B: transposed weights [E][F][D] bf16.

__global__ __launch_bounds__(256, 2) void k_gemm1(
    const unsigned short* __restrict__ xbf,
    const unsigned short* __restrict__ wtg,
    const unsigned short* __restrict__ wtu,
    const int* __restrict__ offsets,
    const int* __restrict__ assign_token,
    unsigned short* __restrict__ act) {
  const int e = blockIdx.z;
  const int row_beg = offsets[e], row_end = offsets[e + 1];
  const int m_base = row_beg + blockIdx.y * 128;
  if (m_base >= row_end) return;
  const int n_base = blockIdx.x * 128;

  __shared__ unsigned short As[128][64];
  __shared__ unsigned short Bg[128][64];
  __shared__ unsigned short Bu[128][64];

  const int tid = threadIdx.x;
  const int lane = tid & 63, wid = tid >> 6;
  const int wr = wid >> 1, wc = wid & 1;
  const int srow = wid * 8 + (lane >> 3);   // staging row (+ i*32)
  const int scol = (lane & 7) * 8;          // staging col (bf16 elems)

  const unsigned short* wg_e = wtg + (size_t)e * FDIM * DMODEL;
  const unsigned short* wu_e = wtu + (size_t)e * FDIM * DMODEL;

  size_t arow[4];
#pragma unroll
  for (int i = 0; i < 4; i++) {
    int slot = m_base + i * 32 + srow;
    if (slot >= row_end) slot = row_end - 1;
    arow[i] = (size_t)assign_token[slot] * DMODEL;
  }

  f32x4 accg[4][4], accu[4][4];
#pragma unroll
  for (int m = 0; m < 4; m++)
#pragma unroll
    for (int n = 0; n < 4; n++) {
      accg[m][n] = f32x4{0.f, 0.f, 0.f, 0.f};
      accu[m][n] = f32x4{0.f, 0.f, 0.f, 0.f};
    }

  for (int k0 = 0; k0 < DMODEL; k0 += 64) {
    __syncthreads();
#pragma unroll
    for (int i = 0; i < 4; i++)
      g2l16(xbf + arow[i] + k0 + scol, &As[i * 32 + srow][scol]);
#pragma unroll
    for (int i = 0; i < 4; i++)
      g2l16(wg_e + (size_t)(n_base + i * 32 + srow) * DMODEL + k0 + scol, &Bg[i * 32 + srow][scol]);
#pragma unroll
    for (int i = 0; i < 4; i++)
      g2l16(wu_e + (size_t)(n_base + i * 32 + srow) * DMODEL + k0 + scol, &Bu[i * 32 + srow][scol]);
    __syncthreads();

#pragma unroll
    for (int kk = 0; kk < 2; kk++) {
      const int ko = kk * 32 + (lane >> 4) * 8;
      bf16x8 a[4], bg[4], bu[4];
#pragma unroll
      for (int m = 0; m < 4; m++)
        a[m] = *(const bf16x8*)&As[wr * 64 + m * 16 + (lane & 15)][ko];
#pragma unroll
      for (int n = 0; n < 4; n++) {
        bg[n] = *(const bf16x8*)&Bg[wc * 64 + n * 16 + (lane & 15)][ko];
        bu[n] = *(const bf16x8*)&Bu[wc * 64 + n * 16 + (lane & 15)][ko];
      }
#pragma unroll
      for (int m = 0; m < 4; m++)
#pragma unroll
        for (int n = 0; n < 4; n++) {
          accg[m][n] = __builtin_amdgcn_mfma_f32_16x16x32_bf16(a[m], bg[n], accg[m][n], 0, 0, 0);
          accu[m][n] = __builtin_amdgcn_mfma_f32_16x16x32_bf16(a[m], bu[n], accu[m][n], 0, 0, 0);
        }
    }
  }

  const int cr = (lane >> 4) * 4;
  const int ccc = lane & 15;
#pragma unroll
  for (int m = 0; m < 4; m++) {
#pragma unroll
    for (int j = 0; j < 4; j++) {
      int slot = m_base + wr * 64 + m * 16 + cr + j;
      if (slot < row_end) {
        unsigned short* dst = act + (size_t)slot * FDIM + n_base + wc * 64 + ccc;
#pragma unroll
        for (int n = 0; n < 4; n++) {
          float g = accg[m][n][j], u = accu[m][n][j];
          float h = (g / (1.0f + __expf(-g))) * u;
          dst[n * 16] = f2bf(h);
        }
      }
    }
  }
}

// ---------------- GEMM2: out_pa = (act @ Wd) * w, per expert ----------------

__global__ __launch_bounds__(256, 2) void k_gemm2(
    const unsigned short* __restrict__ act,
    const unsigned short* __restrict__ wtd,
    const int* __restrict__ offsets,
    const float* __restrict__ assign_w,
    unsigned short* __restrict__ out_pa) {
  const int e = blockIdx.z;
  const int row_beg = offsets[e], row_end = offsets[e + 1];
  const int m_base = row_beg + blockIdx.y * 128;
  if (m_base >= row_end) return;
  const int n_base = blockIdx.x * 128;

  __shared__ unsigned short As[128][64];
  __shared__ unsigned short Bs[128][64];

  const int tid = threadIdx.x;
  const int lane = tid & 63, wid = tid >> 6;
  const int wr = wid >> 1, wc = wid & 1;
  const int srow = wid * 8 + (lane >> 3);
  const int scol = (lane & 7) * 8;

  const unsigned short* wd_e = wtd + (size_t)e * DMODEL * FDIM;

  size_t arow[4];
#pragma unroll
  for (int i = 0; i < 4; i++) {
    int slot = m_base + i * 32 + srow;
    if (slot >= row_end) slot = row_end - 1;
    arow[i] = (size_t)slot * FDIM;
  }

  f32x4 acc[4][4];
#pragma unroll
  for (int m = 0; m < 4; m++)
#pragma unroll
    for (int n = 0; n < 4; n++) acc[m][n] = f32x4{0.f, 0.f, 0.f, 0.f};

  for (int k0 = 0; k0 < FDIM; k0 += 64) {
    __syncthreads();
#pragma unroll
    for (int i = 0; i < 4; i++)
      g2l16(act + arow[i] + k0 + scol, &As[i * 32 + srow][scol]);
#pragma unroll
    for (int i = 0; i < 4; i++)
      g2l16(wd_e + (size_t)(n_base + i * 32 + srow) * FDIM + k0 + scol, &Bs[i * 32 + srow][scol]);
    __syncthreads();

#pragma unroll
    for (int kk = 0; kk < 2; kk++) {
      const int ko = kk * 32 + (lane >> 4) * 8;
      bf16x8 a[4], b[4];
#pragma unroll
      for (int m = 0; m < 4; m++)
        a[m] = *(const bf16x8*)&As[wr * 64 + m * 16 + (lane & 15)][ko];
#pragma unroll
      for (int n = 0; n < 4; n++)
        b[n] = *(const bf16x8*)&Bs[wc * 64 + n * 16 + (lane & 15)][ko];
#pragma unroll
      for (int m = 0; m < 4; m++)
#pragma unroll
        for (int n = 0; n < 4; n++)
          acc[m][n] = __builtin_amdgcn_mfma_f32_16x16x32_bf16(a[m], b[n], acc[m][n], 0, 0, 0);
    }
  }

  const int cr = (lane >> 4) * 4;
  const int ccc = lane & 15;
#pragma unroll
  for (int m = 0; m < 4; m++) {
#pragma unroll
    for (int j = 0; j < 4; j++) {
      int slot = m_base + wr * 64 + m * 16 + cr + j;
      if (slot < row_end) {
        float w = assign_w[slot];
        unsigned short* dst = out_pa + (size_t)slot * DMODEL + n_base + wc * 64 + ccc;
#pragma unroll
        for (int n = 0; n < 4; n++)
          dst[n * 16] = f2bf(acc[m][n][j] * w);
      }
    }
  }
}

__global__ void k_combine(const unsigned short* __restrict__ out_pa,
                          const int* __restrict__ tok2pos,
                          float* __restrict__ out) {
  int t = blockIdx.x;
  int p0 = tok2pos[t * 2], p1 = tok2pos[t * 2 + 1];
  int c = threadIdx.x;
  const ushort4* a = (const ushort4*)(out_pa + (size_t)p0 * DMODEL + c * 8);
  const ushort4* b = (const ushort4*)(out_pa + (size_t)p1 * DMODEL + c * 8);
  ushort4 a0 = a[0], a1 = a[1], b0 = b[0], b1 = b[1];
  float* o = out + (size_t)t * DMODEL + c * 8;
  o[0] = bf2f(a0.x) + bf2f(b0.x);
  o[1] = bf2f(a0.y) + bf2f(b0.y);
  o[2] = bf2f(a0.z) + bf2f(b0.z);
  o[3] = bf2f(a0.w) + bf2f(b0.w);
  o[4] = bf2f(a1.x) + bf2f(b1.x);
  o[5] = bf2f(a1.y) + bf2f(b1.y);
  o[6] = bf2f(a1.z) + bf2f(b1.z);
  o[7] = bf2f(a1.w) + bf2f(b1.w);
}

// ---------------- host ----------------

extern "C" void kernel_launch(void* const* d_in, const int* in_sizes, int n_in,
                              void* d_out, int out_size, void* d_ws, size_t ws_size,
                              hipStream_t stream) {
  const float* x  = (const float*)d_in[0];
  const float* rw = (const float*)d_in[1];
  const float* gw = (const float*)d_in[2];
  const float* uw = (const float*)d_in[3];
  const float* dw = (const float*)d_in[4];
  float* out = (float*)d_out;

  char* ws = (char*)d_ws;
  size_t off = 0;
  auto alloc = [&](size_t bytes) {
    size_t o = off;
    off += (bytes + 255) & ~(size_t)255;
    return o;
  };
  unsigned short* xbf    = (unsigned short*)(ws + alloc((size_t)BT * DMODEL * 2));
  unsigned short* wtg    = (unsigned short*)(ws + alloc((size_t)NEXP * FDIM * DMODEL * 2));
  unsigned short* wtu    = (unsigned short*)(ws + alloc((size_t)NEXP * FDIM * DMODEL * 2));
  unsigned short* wtd    = (unsigned short*)(ws + alloc((size_t)NEXP * DMODEL * FDIM * 2));
  unsigned short* act    = (unsigned short*)(ws + alloc((size_t)NA * FDIM * 2));
  unsigned short* out_pa = (unsigned short*)(ws + alloc((size_t)NA * DMODEL * 2));
  int*   counts  = (int*)(ws + alloc(NEXP * 4));
  int*   offsets = (int*)(ws + alloc((NEXP + 1) * 4));
  int*   cursors = (int*)(ws + alloc(NEXP * 4));
  int*   tok_e   = (int*)(ws + alloc(NA * 4));
  float* tok_w   = (float*)(ws + alloc(NA * 4));
  int*   assign_token = (int*)(ws + alloc(NA * 4));
  float* assign_w     = (float*)(ws + alloc(NA * 4));
  int*   tok2pos      = (int*)(ws + alloc(NA * 4));
  if (off > ws_size) return;  // workspace too small -> fail loudly (poison stays)

  k_zero<<<1, 64, 0, stream>>>(counts, cursors);
  k_convert_x<<<dim3((BT * DMODEL) / (256 * 8)), 256, 0, stream>>>(x, xbf);
  k_transpose<<<dim3(FDIM / 64, DMODEL / 64, NEXP), 256, 0, stream>>>(gw, wtg, DMODEL, FDIM);
  k_transpose<<<dim3(FDIM / 64, DMODEL / 64, NEXP), 256, 0, stream>>>(uw, wtu, DMODEL, FDIM);
  k_transpose<<<dim3(DMODEL / 64, FDIM / 64, NEXP), 256, 0, stream>>>(dw, wtd, FDIM, DMODEL);
  k_router<<<BT / 4, 256, 0, stream>>>(x, rw, tok_e, tok_w, counts);
  k_scan<<<1, 1, 0, stream>>>(counts, offsets);
  k_scatter<<<NA / 256, 256, 0, stream>>>(tok_e, tok_w, offsets, cursors,
                                          assign_token, assign_w, tok2pos);
  k_gemm1<<<dim3(FDIM / 128, NA / 128, NEXP), 256, 0, stream>>>(xbf, wtg, wtu, offsets,
                                                                assign_token, act);
  k_gemm2<<<dim3(DMODEL / 128, NA / 128, NEXP), 256, 0, stream>>>(act, wtd, offsets,
                                                                  assign_w, out_pa);
  k_combine<<<BT, 256, 0, stream>>>(out_pa, tok2pos, out);
}

// Round 2
// 401.261 us; speedup vs baseline: 1.0776x; 1.0776x over previous
//
#include <hip/hip_runtime.h>
#include <stdint.h>

#define BT 4096
#define DMODEL 2048
#define FDIM 1024
#define NEXP 8
#define NA (BT * 2)
#define MAXTILES 72   // 8192/128 + 8

typedef __attribute__((ext_vector_type(8))) __bf16 bf16x8;
typedef __attribute__((ext_vector_type(4))) float f32x4;

__device__ __forceinline__ unsigned short f2bf(float f) {
  union { float f; unsigned int u; } v; v.f = f;
  unsigned int u = v.u;
  unsigned int r = (u + 0x7fffu + ((u >> 16) & 1u)) >> 16;
  return (unsigned short)r;
}
__device__ __forceinline__ float bf2f(unsigned short h) {
  union { unsigned int u; float f; } v; v.u = ((unsigned int)h) << 16;
  return v.f;
}

__device__ __forceinline__ void g2l16(const void* g, void* l) {
  __builtin_amdgcn_global_load_lds((const __attribute__((address_space(1))) void*)g,
                                   (__attribute__((address_space(3))) void*)l, 16, 0, 0);
}

// ---------------- small kernels ----------------

__global__ void k_zero(int* counts, int* cursors) {
  int i = threadIdx.x;
  if (i < NEXP) { counts[i] = 0; cursors[i] = 0; }
}

__global__ void k_convert_x(const float* __restrict__ x, unsigned short* __restrict__ xbf) {
  size_t i = ((size_t)blockIdx.x * 256 + threadIdx.x) * 8;
  float4 a = *(const float4*)(x + i);
  float4 b = *(const float4*)(x + i + 4);
  ushort4 lo = make_ushort4(f2bf(a.x), f2bf(a.y), f2bf(a.z), f2bf(a.w));
  ushort4 hi = make_ushort4(f2bf(b.x), f2bf(b.y), f2bf(b.z), f2bf(b.w));
  *(ushort4*)(xbf + i) = lo;
  *(ushort4*)(xbf + i + 4) = hi;
}

// transpose+convert: src [E][K][N] f32  ->  dst [E][N][K] bf16
__global__ void k_transpose(const float* __restrict__ src, unsigned short* __restrict__ dst,
                            int K, int N) {
  __shared__ float tile[64][65];
  int e = blockIdx.z;
  src += (size_t)e * K * N;
  dst += (size_t)e * K * N;
  int n0 = blockIdx.x * 64, k0 = blockIdx.y * 64;
  int rr = threadIdx.x >> 4, cc = threadIdx.x & 15;
#pragma unroll
  for (int i = 0; i < 4; i++) {
    int k = rr + i * 16;
    float4 v = *(const float4*)(src + (size_t)(k0 + k) * N + n0 + cc * 4);
    tile[k][cc * 4 + 0] = v.x; tile[k][cc * 4 + 1] = v.y;
    tile[k][cc * 4 + 2] = v.z; tile[k][cc * 4 + 3] = v.w;
  }
  __syncthreads();
#pragma unroll
  for (int i = 0; i < 4; i++) {
    int n = rr + i * 16;
    ushort4 o = make_ushort4(f2bf(tile[cc * 4 + 0][n]), f2bf(tile[cc * 4 + 1][n]),
                             f2bf(tile[cc * 4 + 2][n]), f2bf(tile[cc * 4 + 3][n]));
    *(ushort4*)(dst + (size_t)(n0 + n) * K + k0 + cc * 4) = o;
  }
}

__global__ void k_router(const float* __restrict__ x, const float* __restrict__ rw,
                         int* __restrict__ tok_e, float* __restrict__ tok_w,
                         int* __restrict__ counts) {
  int wid = threadIdx.x >> 6;
  int lane = threadIdx.x & 63;
  int t = blockIdx.x * 4 + wid;
  float acc[8];
#pragma unroll
  for (int e = 0; e < 8; e++) acc[e] = 0.0f;
  const float* xr = x + (size_t)t * DMODEL;
  for (int d = lane; d < DMODEL; d += 64) {
    float xv = xr[d];
    const float4* r4 = (const float4*)(rw + d * NEXP);
    float4 ra = r4[0], rb = r4[1];
    acc[0] += xv * ra.x; acc[1] += xv * ra.y; acc[2] += xv * ra.z; acc[3] += xv * ra.w;
    acc[4] += xv * rb.x; acc[5] += xv * rb.y; acc[6] += xv * rb.z; acc[7] += xv * rb.w;
  }
#pragma unroll
  for (int e = 0; e < 8; e++) {
    float v = acc[e];
#pragma unroll
    for (int off = 32; off > 0; off >>= 1) v += __shfl_xor(v, off);
    acc[e] = v;
  }
  if (lane == 0) {
    int e0 = 0; float s0 = acc[0];
#pragma unroll
    for (int e = 1; e < 8; e++) if (acc[e] > s0) { s0 = acc[e]; e0 = e; }
    int e1 = (e0 == 0) ? 1 : 0; float s1 = acc[e1];
#pragma unroll
    for (int e = 0; e < 8; e++) if (e != e0 && acc[e] > s1) { s1 = acc[e]; e1 = e; }
    float w0 = 1.0f / (1.0f + __expf(s1 - s0));
    tok_e[t * 2] = e0; tok_e[t * 2 + 1] = e1;
    tok_w[t * 2] = w0; tok_w[t * 2 + 1] = 1.0f - w0;
    atomicAdd(&counts[e0], 1);
    atomicAdd(&counts[e1], 1);
  }
}

// scan + build compact tile table: tile ti -> (expert, y-tile-within-expert)
__global__ void k_scan(const int* __restrict__ counts, int* __restrict__ offsets,
                       int* __restrict__ tile_e, int* __restrict__ tile_y,
                       int* __restrict__ ntiles) {
  if (threadIdx.x == 0) {
    int s = 0;
    for (int e = 0; e < NEXP; e++) { offsets[e] = s; s += counts[e]; }
    offsets[NEXP] = s;
    int idx = 0;
    for (int e = 0; e < NEXP; e++) {
      int nt = (counts[e] + 127) >> 7;
      for (int y = 0; y < nt; y++) { tile_e[idx] = e; tile_y[idx] = y; idx++; }
    }
    *ntiles = idx;
    for (int i = idx; i < MAXTILES; i++) { tile_e[i] = 0; tile_y[i] = 0; }
  }
}

__global__ void k_scatter(const int* __restrict__ tok_e, const float* __restrict__ tok_w,
                          const int* __restrict__ offsets, int* __restrict__ cursors,
                          int* __restrict__ assign_token, float* __restrict__ assign_w,
                          int* __restrict__ tok2pos) {
  int i = blockIdx.x * 256 + threadIdx.x;
  if (i >= NA) return;
  int e = tok_e[i];
  int pos = offsets[e] + atomicAdd(&cursors[e], 1);
  assign_token[pos] = i >> 1;
  assign_w[pos] = tok_w[i];
  tok2pos[i] = pos;
}

// ---------------- GEMM1: act = silu(Xg @ Wg) * (Xg @ Wu), per expert ----------------
// T2 XOR swizzle: LDS[r][jb16] holds global col-block (jb16 ^ (r&7)); written via
// pre-swizzled global source (linear LDS dest for global_load_lds), read with XOR.

__global__ __launch_bounds__(256, 2) void k_gemm1(
    const unsigned short* __restrict__ xbf,
    const unsigned short* __restrict__ wtg,
    const unsigned short* __restrict__ wtu,
    const int* __restrict__ offsets,
    const int* __restrict__ tile_e, const int* __restrict__ tile_y,
    const int* __restrict__ ntiles,
    const int* __restrict__ assign_token,
    unsigned short* __restrict__ act) {
  const int ti = blockIdx.y;
  if (ti >= *ntiles) return;
  const int e = tile_e[ti];
  const int row_beg = offsets[e], row_end = offsets[e + 1];
  const int m_base = row_beg + tile_y[ti] * 128;
  const int n_base = blockIdx.x * 128;

  __shared__ unsigned short As[128][64];
  __shared__ unsigned short Bg[128][64];
  __shared__ unsigned short Bu[128][64];

  const int tid = threadIdx.x;
  const int lane = tid & 63, wid = tid >> 6;
  const int wr = wid >> 1, wc = wid & 1;
  const int srow = wid * 8 + (lane >> 3);              // staging row (+ i*32); row&7 = lane>>3
  const int scol_d = (lane & 7) * 8;                   // LDS dest col (linear, lane*16B)
  const int scol_s = ((lane & 7) ^ (lane >> 3)) * 8;   // pre-swizzled global source col
  const int sw = (lane & 7) * 8;                       // read-side XOR (row&7 == lane&7)

  const unsigned short* wg_e = wtg + (size_t)e * FDIM * DMODEL;
  const unsigned short* wu_e = wtu + (size_t)e * FDIM * DMODEL;

  size_t arow[4];
#pragma unroll
  for (int i = 0; i < 4; i++) {
    int slot = m_base + i * 32 + srow;
    if (slot >= row_end) slot = row_end - 1;
    arow[i] = (size_t)assign_token[slot] * DMODEL;
  }

  f32x4 accg[4][4], accu[4][4];
#pragma unroll
  for (int m = 0; m < 4; m++)
#pragma unroll
    for (int n = 0; n < 4; n++) {
      accg[m][n] = f32x4{0.f, 0.f, 0.f, 0.f};
      accu[m][n] = f32x4{0.f, 0.f, 0.f, 0.f};
    }

  for (int k0 = 0; k0 < DMODEL; k0 += 64) {
    __syncthreads();
#pragma unroll
    for (int i = 0; i < 4; i++)
      g2l16(xbf + arow[i] + k0 + scol_s, &As[i * 32 + srow][scol_d]);
#pragma unroll
    for (int i = 0; i < 4; i++)
      g2l16(wg_e + (size_t)(n_base + i * 32 + srow) * DMODEL + k0 + scol_s, &Bg[i * 32 + srow][scol_d]);
#pragma unroll
    for (int i = 0; i < 4; i++)
      g2l16(wu_e + (size_t)(n_base + i * 32 + srow) * DMODEL + k0 + scol_s, &Bu[i * 32 + srow][scol_d]);
    __syncthreads();

#pragma unroll
    for (int kk = 0; kk < 2; kk++) {
      const int ko = kk * 32 + (lane >> 4) * 8;
      bf16x8 a[4], bg[4], bu[4];
#pragma unroll
      for (int m = 0; m < 4; m++)
        a[m] = *(const bf16x8*)&As[wr * 64 + m * 16 + (lane & 15)][ko ^ sw];
#pragma unroll
      for (int n = 0; n < 4; n++) {
        bg[n] = *(const bf16x8*)&Bg[wc * 64 + n * 16 + (lane & 15)][ko ^ sw];
        bu[n] = *(const bf16x8*)&Bu[wc * 64 + n * 16 + (lane & 15)][ko ^ sw];
      }
#pragma unroll
      for (int m = 0; m < 4; m++)
#pragma unroll
        for (int n = 0; n < 4; n++) {
          accg[m][n] = __builtin_amdgcn_mfma_f32_16x16x32_bf16(a[m], bg[n], accg[m][n], 0, 0, 0);
          accu[m][n] = __builtin_amdgcn_mfma_f32_16x16x32_bf16(a[m], bu[n], accu[m][n], 0, 0, 0);
        }
    }
  }

  const int cr = (lane >> 4) * 4;
  const int ccc = lane & 15;
#pragma unroll
  for (int m = 0; m < 4; m++) {
#pragma unroll
    for (int j = 0; j < 4; j++) {
      int slot = m_base + wr * 64 + m * 16 + cr + j;
      if (slot < row_end) {
        unsigned short* dst = act + (size_t)slot * FDIM + n_base + wc * 64 + ccc;
#pragma unroll
        for (int n = 0; n < 4; n++) {
          float g = accg[m][n][j], u = accu[m][n][j];
          float h = (g / (1.0f + __expf(-g))) * u;
          dst[n * 16] = f2bf(h);
        }
      }
    }
  }
}

// ---------------- GEMM2: out_pa = (act @ Wd) * w, per expert ----------------

__global__ __launch_bounds__(256, 2) void k_gemm2(
    const unsigned short* __restrict__ act,
    const unsigned short* __restrict__ wtd,
    const int* __restrict__ offsets,
    const int* __restrict__ tile_e, const int* __restrict__ tile_y,
    const int* __restrict__ ntiles,
    const float* __restrict__ assign_w,
    unsigned short* __restrict__ out_pa) {
  const int ti = blockIdx.y;
  if (ti >= *ntiles) return;
  const int e = tile_e[ti];
  const int row_beg = offsets[e], row_end = offsets[e + 1];
  const int m_base = row_beg + tile_y[ti] * 128;
  const int n_base = blockIdx.x * 128;

  __shared__ unsigned short As[128][64];
  __shared__ unsigned short Bs[128][64];

  const int tid = threadIdx.x;
  const int lane = tid & 63, wid = tid >> 6;
  const int wr = wid >> 1, wc = wid & 1;
  const int srow = wid * 8 + (lane >> 3);
  const int scol_d = (lane & 7) * 8;
  const int scol_s = ((lane & 7) ^ (lane >> 3)) * 8;
  const int sw = (lane & 7) * 8;

  const unsigned short* wd_e = wtd + (size_t)e * DMODEL * FDIM;

  size_t arow[4];
#pragma unroll
  for (int i = 0; i < 4; i++) {
    int slot = m_base + i * 32 + srow;
    if (slot >= row_end) slot = row_end - 1;
    arow[i] = (size_t)slot * FDIM;
  }

  f32x4 acc[4][4];
#pragma unroll
  for (int m = 0; m < 4; m++)
#pragma unroll
    for (int n = 0; n < 4; n++) acc[m][n] = f32x4{0.f, 0.f, 0.f, 0.f};

  for (int k0 = 0; k0 < FDIM; k0 += 64) {
    __syncthreads();
#pragma unroll
    for (int i = 0; i < 4; i++)
      g2l16(act + arow[i] + k0 + scol_s, &As[i * 32 + srow][scol_d]);
#pragma unroll
    for (int i = 0; i < 4; i++)
      g2l16(wd_e + (size_t)(n_base + i * 32 + srow) * FDIM + k0 + scol_s, &Bs[i * 32 + srow][scol_d]);
    __syncthreads();

#pragma unroll
    for (int kk = 0; kk < 2; kk++) {
      const int ko = kk * 32 + (lane >> 4) * 8;
      bf16x8 a[4], b[4];
#pragma unroll
      for (int m = 0; m < 4; m++)
        a[m] = *(const bf16x8*)&As[wr * 64 + m * 16 + (lane & 15)][ko ^ sw];
#pragma unroll
      for (int n = 0; n < 4; n++)
        b[n] = *(const bf16x8*)&Bs[wc * 64 + n * 16 + (lane & 15)][ko ^ sw];
#pragma unroll
      for (int m = 0; m < 4; m++)
#pragma unroll
        for (int n = 0; n < 4; n++)
          acc[m][n] = __builtin_amdgcn_mfma_f32_16x16x32_bf16(a[m], b[n], acc[m][n], 0, 0, 0);
    }
  }

  const int cr = (lane >> 4) * 4;
  const int ccc = lane & 15;
#pragma unroll
  for (int m = 0; m < 4; m++) {
#pragma unroll
    for (int j = 0; j < 4; j++) {
      int slot = m_base + wr * 64 + m * 16 + cr + j;
      if (slot < row_end) {
        float w = assign_w[slot];
        unsigned short* dst = out_pa + (size_t)slot * DMODEL + n_base + wc * 64 + ccc;
#pragma unroll
        for (int n = 0; n < 4; n++)
          dst[n * 16] = f2bf(acc[m][n][j] * w);
      }
    }
  }
}

__global__ void k_combine(const unsigned short* __restrict__ out_pa,
                          const int* __restrict__ tok2pos,
                          float* __restrict__ out) {
  int t = blockIdx.x;
  int p0 = tok2pos[t * 2], p1 = tok2pos[t * 2 + 1];
  int c = threadIdx.x;
  const ushort4* a = (const ushort4*)(out_pa + (size_t)p0 * DMODEL + c * 8);
  const ushort4* b = (const ushort4*)(out_pa + (size_t)p1 * DMODEL + c * 8);
  ushort4 a0 = a[0], a1 = a[1], b0 = b[0], b1 = b[1];
  float* o = out + (size_t)t * DMODEL + c * 8;
  o[0] = bf2f(a0.x) + bf2f(b0.x);
  o[1] = bf2f(a0.y) + bf2f(b0.y);
  o[2] = bf2f(a0.z) + bf2f(b0.z);
  o[3] = bf2f(a0.w) + bf2f(b0.w);
  o[4] = bf2f(a1.x) + bf2f(b1.x);
  o[5] = bf2f(a1.y) + bf2f(b1.y);
  o[6] = bf2f(a1.z) + bf2f(b1.z);
  o[7] = bf2f(a1.w) + bf2f(b1.w);
}

// ---------------- host ----------------

extern "C" void kernel_launch(void* const* d_in, const int* in_sizes, int n_in,
                              void* d_out, int out_size, void* d_ws, size_t ws_size,
                              hipStream_t stream) {
  const float* x  = (const float*)d_in[0];
  const float* rw = (const float*)d_in[1];
  const float* gw = (const float*)d_in[2];
  const float* uw = (const float*)d_in[3];
  const float* dw = (const float*)d_in[4];
  float* out = (float*)d_out;

  char* ws = (char*)d_ws;
  size_t off = 0;
  auto alloc = [&](size_t bytes) {
    size_t o = off;
    off += (bytes + 255) & ~(size_t)255;
    return o;
  };
  unsigned short* xbf    = (unsigned short*)(ws + alloc((size_t)BT * DMODEL * 2));
  unsigned short* wtg    = (unsigned short*)(ws + alloc((size_t)NEXP * FDIM * DMODEL * 2));
  unsigned short* wtu    = (unsigned short*)(ws + alloc((size_t)NEXP * FDIM * DMODEL * 2));
  unsigned short* wtd    = (unsigned short*)(ws + alloc((size_t)NEXP * DMODEL * FDIM * 2));
  unsigned short* act    = (unsigned short*)(ws + alloc((size_t)NA * FDIM * 2));
  unsigned short* out_pa = (unsigned short*)(ws + alloc((size_t)NA * DMODEL * 2));
  int*   counts  = (int*)(ws + alloc(NEXP * 4));
  int*   offsets = (int*)(ws + alloc((NEXP + 1) * 4));
  int*   cursors = (int*)(ws + alloc(NEXP * 4));
  int*   tok_e   = (int*)(ws + alloc(NA * 4));
  float* tok_w   = (float*)(ws + alloc(NA * 4));
  int*   assign_token = (int*)(ws + alloc(NA * 4));
  float* assign_w     = (float*)(ws + alloc(NA * 4));
  int*   tok2pos      = (int*)(ws + alloc(NA * 4));
  int*   tile_e       = (int*)(ws + alloc(MAXTILES * 4));
  int*   tile_y       = (int*)(ws + alloc(MAXTILES * 4));
  int*   ntiles       = (int*)(ws + alloc(4));
  if (off > ws_size) return;  // workspace too small -> fail loudly (poison stays)

  k_zero<<<1, 64, 0, stream>>>(counts, cursors);
  k_convert_x<<<dim3((BT * DMODEL) / (256 * 8)), 256, 0, stream>>>(x, xbf);
  k_transpose<<<dim3(FDIM / 64, DMODEL / 64, NEXP), 256, 0, stream>>>(gw, wtg, DMODEL, FDIM);
  k_transpose<<<dim3(FDIM / 64, DMODEL / 64, NEXP), 256, 0, stream>>>(uw, wtu, DMODEL, FDIM);
  k_transpose<<<dim3(DMODEL / 64, FDIM / 64, NEXP), 256, 0, stream>>>(dw, wtd, FDIM, DMODEL);
  k_router<<<BT / 4, 256, 0, stream>>>(x, rw, tok_e, tok_w, counts);
  k_scan<<<1, 1, 0, stream>>>(counts, offsets, tile_e, tile_y, ntiles);
  k_scatter<<<NA / 256, 256, 0, stream>>>(tok_e, tok_w, offsets, cursors,
                                          assign_token, assign_w, tok2pos);
  k_gemm1<<<dim3(FDIM / 128, MAXTILES), 256, 0, stream>>>(xbf, wtg, wtu, offsets,
                                                          tile_e, tile_y, ntiles,
                                                          assign_token, act);
  k_gemm2<<<dim3(DMODEL / 128, MAXTILES), 256, 0, stream>>>(act, wtd, offsets,
                                                            tile_e, tile_y, ntiles,
                                                            assign_w, out_pa);
  k_combine<<<BT, 256, 0, stream>>>(out_pa, tok2pos, out);
}

// Round 3
// 300.694 us; speedup vs baseline: 1.4379x; 1.3344x over previous
//
#include <hip/hip_runtime.h>
#include <stdint.h>

#define BT 4096
#define DMODEL 2048
#define FDIM 1024
#define NEXP 8
#define NA (BT * 2)
#define MAXTILES 72   // 8192/128 + 8

typedef __attribute__((ext_vector_type(8))) __bf16 bf16x8;
typedef __attribute__((ext_vector_type(4))) float f32x4;

__device__ __forceinline__ unsigned short f2bf(float f) {
  union { float f; unsigned int u; } v; v.f = f;
  unsigned int u = v.u;
  unsigned int r = (u + 0x7fffu + ((u >> 16) & 1u)) >> 16;
  return (unsigned short)r;
}
__device__ __forceinline__ float bf2f(unsigned short h) {
  union { unsigned int u; float f; } v; v.u = ((unsigned int)h) << 16;
  return v.f;
}

__device__ __forceinline__ void g2l16(const void* g, void* l) {
  __builtin_amdgcn_global_load_lds((const __attribute__((address_space(1))) void*)g,
                                   (__attribute__((address_space(3))) void*)l, 16, 0, 0);
}

// ---------------- router (+ x -> bf16 conversion fused) ----------------

__global__ void k_router(const float* __restrict__ x, const float* __restrict__ rw,
                         unsigned short* __restrict__ xbf,
                         int* __restrict__ tok_e, float* __restrict__ tok_w) {
  int wid = threadIdx.x >> 6;
  int lane = threadIdx.x & 63;
  int t = blockIdx.x * 4 + wid;
  float acc[8];
#pragma unroll
  for (int e = 0; e < 8; e++) acc[e] = 0.0f;
  const float* xr = x + (size_t)t * DMODEL;
  unsigned short* xbr = xbf + (size_t)t * DMODEL;
  for (int d = lane; d < DMODEL; d += 64) {
    float xv = xr[d];
    xbr[d] = f2bf(xv);
    const float4* r4 = (const float4*)(rw + d * NEXP);
    float4 ra = r4[0], rb = r4[1];
    acc[0] += xv * ra.x; acc[1] += xv * ra.y; acc[2] += xv * ra.z; acc[3] += xv * ra.w;
    acc[4] += xv * rb.x; acc[5] += xv * rb.y; acc[6] += xv * rb.z; acc[7] += xv * rb.w;
  }
#pragma unroll
  for (int e = 0; e < 8; e++) {
    float v = acc[e];
#pragma unroll
    for (int off = 32; off > 0; off >>= 1) v += __shfl_xor(v, off);
    acc[e] = v;
  }
  if (lane == 0) {
    int e0 = 0; float s0 = acc[0];
#pragma unroll
    for (int e = 1; e < 8; e++) if (acc[e] > s0) { s0 = acc[e]; e0 = e; }
    int e1 = (e0 == 0) ? 1 : 0; float s1 = acc[e1];
#pragma unroll
    for (int e = 0; e < 8; e++) if (e != e0 && acc[e] > s1) { s1 = acc[e]; e1 = e; }
    float w0 = 1.0f / (1.0f + __expf(s1 - s0));
    tok_e[t * 2] = e0; tok_e[t * 2 + 1] = e1;
    tok_w[t * 2] = w0; tok_w[t * 2 + 1] = 1.0f - w0;
  }
}

// histogram + scan + tile table + zero cursors, one launch
__global__ void k_scanbuild(const int* __restrict__ tok_e, int* __restrict__ offsets,
                            int* __restrict__ tile_e, int* __restrict__ tile_y,
                            int* __restrict__ ntiles, int* __restrict__ cursors) {
  __shared__ int hist[NEXP];
  int tid = threadIdx.x;
  if (tid < NEXP) hist[tid] = 0;
  __syncthreads();
  for (int i = tid; i < NA; i += 256) atomicAdd(&hist[tok_e[i]], 1);
  __syncthreads();
  if (tid == 0) {
    int s = 0;
    for (int e = 0; e < NEXP; e++) { offsets[e] = s; s += hist[e]; }
    offsets[NEXP] = s;
    int idx = 0;
    for (int e = 0; e < NEXP; e++) {
      int nt = (hist[e] + 127) >> 7;
      for (int y = 0; y < nt; y++) { tile_e[idx] = e; tile_y[idx] = y; idx++; }
    }
    *ntiles = idx;
    for (int i = idx; i < MAXTILES; i++) { tile_e[i] = 0; tile_y[i] = 0; }
  }
  if (tid < NEXP) cursors[tid] = 0;
}

__global__ void k_scatter(const int* __restrict__ tok_e, const float* __restrict__ tok_w,
                          const int* __restrict__ offsets, int* __restrict__ cursors,
                          int* __restrict__ assign_token, float* __restrict__ assign_w,
                          int* __restrict__ tok2pos) {
  int i = blockIdx.x * 256 + threadIdx.x;
  if (i >= NA) return;
  int e = tok_e[i];
  int pos = offsets[e] + atomicAdd(&cursors[e], 1);
  assign_token[pos] = i >> 1;
  assign_w[pos] = tok_w[i];
  tok2pos[i] = pos;
}

// all three weight transposes, one launch: src [E][K][N] f32 -> dst [E][N][K] bf16
__global__ void k_transpose_all(const float* __restrict__ gw, const float* __restrict__ uw,
                                const float* __restrict__ dw,
                                unsigned short* __restrict__ wtg, unsigned short* __restrict__ wtu,
                                unsigned short* __restrict__ wtd) {
  __shared__ float tile[64][65];
  int z = blockIdx.y;
  const float* src; unsigned short* dst; int N;
  if (z < 8)       { src = gw + (size_t)z * DMODEL * FDIM;        dst = wtg + (size_t)z * DMODEL * FDIM;        N = FDIM; }
  else if (z < 16) { src = uw + (size_t)(z - 8) * DMODEL * FDIM;  dst = wtu + (size_t)(z - 8) * DMODEL * FDIM;  N = FDIM; }
  else             { src = dw + (size_t)(z - 16) * FDIM * DMODEL; dst = wtd + (size_t)(z - 16) * FDIM * DMODEL; N = DMODEL; }
  int ntx = N >> 6;
  int bx = blockIdx.x;
  int n0 = (bx % ntx) * 64, k0 = (bx / ntx) * 64;
  int rr = threadIdx.x >> 4, cc = threadIdx.x & 15;
#pragma unroll
  for (int i = 0; i < 4; i++) {
    int k = rr + i * 16;
    float4 v = *(const float4*)(src + (size_t)(k0 + k) * N + n0 + cc * 4);
    tile[k][cc * 4 + 0] = v.x; tile[k][cc * 4 + 1] = v.y;
    tile[k][cc * 4 + 2] = v.z; tile[k][cc * 4 + 3] = v.w;
  }
  __syncthreads();
  int K = (z < 16) ? DMODEL : FDIM;
#pragma unroll
  for (int i = 0; i < 4; i++) {
    int n = rr + i * 16;
    ushort4 o = make_ushort4(f2bf(tile[cc * 4 + 0][n]), f2bf(tile[cc * 4 + 1][n]),
                             f2bf(tile[cc * 4 + 2][n]), f2bf(tile[cc * 4 + 3][n]));
    *(ushort4*)(dst + (size_t)(n0 + n) * K + k0 + cc * 4) = o;
  }
}

// ---------------- GEMM1: act = silu(Xg @ Wg) * (Xg @ Wu) ----------------
// 512 threads, 8 waves (4x2), 128x128 tile, per-wave 32x64 dual accum.
// T2 swizzle: pre-swizzled global source col + XOR on LDS read.

__global__ __launch_bounds__(512, 4) void k_gemm1(
    const unsigned short* __restrict__ xbf,
    const unsigned short* __restrict__ wtg,
    const unsigned short* __restrict__ wtu,
    const int* __restrict__ offsets,
    const int* __restrict__ tile_e, const int* __restrict__ tile_y,
    const int* __restrict__ ntiles,
    const int* __restrict__ assign_token,
    unsigned short* __restrict__ act) {
  const int ti = blockIdx.y;
  if (ti >= *ntiles) return;
  const int e = tile_e[ti];
  const int row_beg = offsets[e], row_end = offsets[e + 1];
  const int m_base = row_beg + tile_y[ti] * 128;
  const int n_base = blockIdx.x * 128;

  __shared__ unsigned short As[128][64];
  __shared__ unsigned short Bg[128][64];
  __shared__ unsigned short Bu[128][64];

  const int tid = threadIdx.x;
  const int lane = tid & 63, wid = tid >> 6;
  const int wr = wid >> 1, wc = wid & 1;          // 4 x 2 wave grid
  const int srow = tid >> 3;                      // 0..63 (2 rounds cover 128 rows)
  const int scol_d = (tid & 7) * 8;               // linear LDS dest col
  const int scol_s = ((tid & 7) ^ (srow & 7)) * 8;// pre-swizzled global col
  const int sw = (lane & 7) * 8;                  // read-side XOR

  const unsigned short* wg_e = wtg + (size_t)e * FDIM * DMODEL;
  const unsigned short* wu_e = wtu + (size_t)e * FDIM * DMODEL;

  size_t arow[2];
#pragma unroll
  for (int r = 0; r < 2; r++) {
    int slot = m_base + r * 64 + srow;
    if (slot >= row_end) slot = row_end - 1;
    arow[r] = (size_t)assign_token[slot] * DMODEL;
  }

  f32x4 accg[2][4], accu[2][4];
#pragma unroll
  for (int m = 0; m < 2; m++)
#pragma unroll
    for (int n = 0; n < 4; n++) {
      accg[m][n] = f32x4{0.f, 0.f, 0.f, 0.f};
      accu[m][n] = f32x4{0.f, 0.f, 0.f, 0.f};
    }

  for (int k0 = 0; k0 < DMODEL; k0 += 64) {
    __syncthreads();
#pragma unroll
    for (int r = 0; r < 2; r++)
      g2l16(xbf + arow[r] + k0 + scol_s, &As[r * 64 + srow][scol_d]);
#pragma unroll
    for (int r = 0; r < 2; r++)
      g2l16(wg_e + (size_t)(n_base + r * 64 + srow) * DMODEL + k0 + scol_s, &Bg[r * 64 + srow][scol_d]);
#pragma unroll
    for (int r = 0; r < 2; r++)
      g2l16(wu_e + (size_t)(n_base + r * 64 + srow) * DMODEL + k0 + scol_s, &Bu[r * 64 + srow][scol_d]);
    __syncthreads();

#pragma unroll
    for (int kk = 0; kk < 2; kk++) {
      const int ko = kk * 32 + (lane >> 4) * 8;
      bf16x8 a[2];
#pragma unroll
      for (int m = 0; m < 2; m++)
        a[m] = *(const bf16x8*)&As[wr * 32 + m * 16 + (lane & 15)][ko ^ sw];
      {
        bf16x8 b[4];
#pragma unroll
        for (int n = 0; n < 4; n++)
          b[n] = *(const bf16x8*)&Bg[wc * 64 + n * 16 + (lane & 15)][ko ^ sw];
#pragma unroll
        for (int m = 0; m < 2; m++)
#pragma unroll
          for (int n = 0; n < 4; n++)
            accg[m][n] = __builtin_amdgcn_mfma_f32_16x16x32_bf16(a[m], b[n], accg[m][n], 0, 0, 0);
      }
      {
        bf16x8 b[4];
#pragma unroll
        for (int n = 0; n < 4; n++)
          b[n] = *(const bf16x8*)&Bu[wc * 64 + n * 16 + (lane & 15)][ko ^ sw];
#pragma unroll
        for (int m = 0; m < 2; m++)
#pragma unroll
          for (int n = 0; n < 4; n++)
            accu[m][n] = __builtin_amdgcn_mfma_f32_16x16x32_bf16(a[m], b[n], accu[m][n], 0, 0, 0);
      }
    }
  }

  const int cr = (lane >> 4) * 4;
  const int ccc = lane & 15;
#pragma unroll
  for (int m = 0; m < 2; m++) {
#pragma unroll
    for (int j = 0; j < 4; j++) {
      int slot = m_base + wr * 32 + m * 16 + cr + j;
      if (slot < row_end) {
        unsigned short* dst = act + (size_t)slot * FDIM + n_base + wc * 64 + ccc;
#pragma unroll
        for (int n = 0; n < 4; n++) {
          float g = accg[m][n][j], u = accu[m][n][j];
          float h = (g / (1.0f + __expf(-g))) * u;
          dst[n * 16] = f2bf(h);
        }
      }
    }
  }
}

// ---------------- GEMM2: out_pa = (act @ Wd) * w ----------------

__global__ __launch_bounds__(256, 4) void k_gemm2(
    const unsigned short* __restrict__ act,
    const unsigned short* __restrict__ wtd,
    const int* __restrict__ offsets,
    const int* __restrict__ tile_e, const int* __restrict__ tile_y,
    const int* __restrict__ ntiles,
    const float* __restrict__ assign_w,
    unsigned short* __restrict__ out_pa) {
  const int ti = blockIdx.y;
  if (ti >= *ntiles) return;
  const int e = tile_e[ti];
  const int row_beg = offsets[e], row_end = offsets[e + 1];
  const int m_base = row_beg + tile_y[ti] * 128;
  const int n_base = blockIdx.x * 128;

  __shared__ unsigned short As[128][64];
  __shared__ unsigned short Bs[128][64];

  const int tid = threadIdx.x;
  const int lane = tid & 63, wid = tid >> 6;
  const int wr = wid >> 1, wc = wid & 1;
  const int srow = wid * 8 + (lane >> 3);
  const int scol_d = (lane & 7) * 8;
  const int scol_s = ((lane & 7) ^ (lane >> 3)) * 8;
  const int sw = (lane & 7) * 8;

  const unsigned short* wd_e = wtd + (size_t)e * DMODEL * FDIM;

  size_t arow[4];
#pragma unroll
  for (int i = 0; i < 4; i++) {
    int slot = m_base + i * 32 + srow;
    if (slot >= row_end) slot = row_end - 1;
    arow[i] = (size_t)slot * FDIM;
  }

  f32x4 acc[4][4];
#pragma unroll
  for (int m = 0; m < 4; m++)
#pragma unroll
    for (int n = 0; n < 4; n++) acc[m][n] = f32x4{0.f, 0.f, 0.f, 0.f};

  for (int k0 = 0; k0 < FDIM; k0 += 64) {
    __syncthreads();
#pragma unroll
    for (int i = 0; i < 4; i++)
      g2l16(act + arow[i] + k0 + scol_s, &As[i * 32 + srow][scol_d]);
#pragma unroll
    for (int i = 0; i < 4; i++)
      g2l16(wd_e + (size_t)(n_base + i * 32 + srow) * FDIM + k0 + scol_s, &Bs[i * 32 + srow][scol_d]);
    __syncthreads();

#pragma unroll
    for (int kk = 0; kk < 2; kk++) {
      const int ko = kk * 32 + (lane >> 4) * 8;
      bf16x8 a[4], b[4];
#pragma unroll
      for (int m = 0; m < 4; m++)
        a[m] = *(const bf16x8*)&As[wr * 64 + m * 16 + (lane & 15)][ko ^ sw];
#pragma unroll
      for (int n = 0; n < 4; n++)
        b[n] = *(const bf16x8*)&Bs[wc * 64 + n * 16 + (lane & 15)][ko ^ sw];
#pragma unroll
      for (int m = 0; m < 4; m++)
#pragma unroll
        for (int n = 0; n < 4; n++)
          acc[m][n] = __builtin_amdgcn_mfma_f32_16x16x32_bf16(a[m], b[n], acc[m][n], 0, 0, 0);
    }
  }

  const int cr = (lane >> 4) * 4;
  const int ccc = lane & 15;
#pragma unroll
  for (int m = 0; m < 4; m++) {
#pragma unroll
    for (int j = 0; j < 4; j++) {
      int slot = m_base + wr * 64 + m * 16 + cr + j;
      if (slot < row_end) {
        float w = assign_w[slot];
        unsigned short* dst = out_pa + (size_t)slot * DMODEL + n_base + wc * 64 + ccc;
#pragma unroll
        for (int n = 0; n < 4; n++)
          dst[n * 16] = f2bf(acc[m][n][j] * w);
      }
    }
  }
}

__global__ void k_combine(const unsigned short* __restrict__ out_pa,
                          const int* __restrict__ tok2pos,
                          float* __restrict__ out) {
  int t = blockIdx.x;
  int p0 = tok2pos[t * 2], p1 = tok2pos[t * 2 + 1];
  int c = threadIdx.x;
  const ushort4* a = (const ushort4*)(out_pa + (size_t)p0 * DMODEL + c * 8);
  const ushort4* b = (const ushort4*)(out_pa + (size_t)p1 * DMODEL + c * 8);
  ushort4 a0 = a[0], a1 = a[1], b0 = b[0], b1 = b[1];
  float* o = out + (size_t)t * DMODEL + c * 8;
  o[0] = bf2f(a0.x) + bf2f(b0.x);
  o[1] = bf2f(a0.y) + bf2f(b0.y);
  o[2] = bf2f(a0.z) + bf2f(b0.z);
  o[3] = bf2f(a0.w) + bf2f(b0.w);
  o[4] = bf2f(a1.x) + bf2f(b1.x);
  o[5] = bf2f(a1.y) + bf2f(b1.y);
  o[6] = bf2f(a1.z) + bf2f(b1.z);
  o[7] = bf2f(a1.w) + bf2f(b1.w);
}

// ---------------- host ----------------

extern "C" void kernel_launch(void* const* d_in, const int* in_sizes, int n_in,
                              void* d_out, int out_size, void* d_ws, size_t ws_size,
                              hipStream_t stream) {
  const float* x  = (const float*)d_in[0];
  const float* rw = (const float*)d_in[1];
  const float* gw = (const float*)d_in[2];
  const float* uw = (const float*)d_in[3];
  const float* dw = (const float*)d_in[4];
  float* out = (float*)d_out;

  char* ws = (char*)d_ws;
  size_t off = 0;
  auto alloc = [&](size_t bytes) {
    size_t o = off;
    off += (bytes + 255) & ~(size_t)255;
    return o;
  };
  unsigned short* xbf    = (unsigned short*)(ws + alloc((size_t)BT * DMODEL * 2));
  unsigned short* wtg    = (unsigned short*)(ws + alloc((size_t)NEXP * FDIM * DMODEL * 2));
  unsigned short* wtu    = (unsigned short*)(ws + alloc((size_t)NEXP * FDIM * DMODEL * 2));
  unsigned short* wtd    = (unsigned short*)(ws + alloc((size_t)NEXP * DMODEL * FDIM * 2));
  unsigned short* act    = (unsigned short*)(ws + alloc((size_t)NA * FDIM * 2));
  unsigned short* out_pa = (unsigned short*)(ws + alloc((size_t)NA * DMODEL * 2));
  int*   offsets = (int*)(ws + alloc((NEXP + 1) * 4));
  int*   cursors = (int*)(ws + alloc(NEXP * 4));
  int*   tok_e   = (int*)(ws + alloc(NA * 4));
  float* tok_w   = (float*)(ws + alloc(NA * 4));
  int*   assign_token = (int*)(ws + alloc(NA * 4));
  float* assign_w     = (float*)(ws + alloc(NA * 4));
  int*   tok2pos      = (int*)(ws + alloc(NA * 4));
  int*   tile_e       = (int*)(ws + alloc(MAXTILES * 4));
  int*   tile_y       = (int*)(ws + alloc(MAXTILES * 4));
  int*   ntiles       = (int*)(ws + alloc(4));
  if (off > ws_size) return;  // workspace too small -> fail loudly (poison stays)

  k_router<<<BT / 4, 256, 0, stream>>>(x, rw, xbf, tok_e, tok_w);
  k_scanbuild<<<1, 256, 0, stream>>>(tok_e, offsets, tile_e, tile_y, ntiles, cursors);
  k_scatter<<<NA / 256, 256, 0, stream>>>(tok_e, tok_w, offsets, cursors,
                                          assign_token, assign_w, tok2pos);
  k_transpose_all<<<dim3(512, 24), 256, 0, stream>>>(gw, uw, dw, wtg, wtu, wtd);
  k_gemm1<<<dim3(FDIM / 128, MAXTILES), 512, 0, stream>>>(xbf, wtg, wtu, offsets,
                                                          tile_e, tile_y, ntiles,
                                                          assign_token, act);
  k_gemm2<<<dim3(DMODEL / 128, MAXTILES), 256, 0, stream>>>(act, wtd, offsets,
                                                            tile_e, tile_y, ntiles,
                                                            assign_w, out_pa);
  k_combine<<<BT, 256, 0, stream>>>(out_pa, tok2pos, out);
}